// Round 8
// baseline (704.198 us; speedup 1.0000x reference)
//
#include <hip/hip_runtime.h>

#define N_NODES 100000
#define N_EDGES 1600000

// ---------------- degree ----------------
__global__ void deg_kernel(const int* __restrict__ dst, int* __restrict__ deg, int E) {
    int i = blockIdx.x * blockDim.x + threadIdx.x;
    if (i < E) atomicAdd(&deg[dst[i]], 1);
}

__global__ void dinv_kernel(const int* __restrict__ deg, float* __restrict__ dinv, int n) {
    int i = blockIdx.x * blockDim.x + threadIdx.x;
    if (i < n) dinv[i] = rsqrtf((float)(deg[i] + 1));   // +1 = self-loop
}

// ---------------- exclusive scan of deg -> rowptr (3 passes) ----------------
__global__ void scan_sums_kernel(const int* __restrict__ deg, int* __restrict__ bsums, int n) {
    __shared__ int sd[256];
    int t = threadIdx.x;
    int base = blockIdx.x * 1024 + t * 4;
    int s = 0;
    #pragma unroll
    for (int j = 0; j < 4; ++j) { int i = base + j; if (i < n) s += deg[i]; }
    sd[t] = s; __syncthreads();
    for (int off = 128; off > 0; off >>= 1) {
        if (t < off) sd[t] += sd[t + off];
        __syncthreads();
    }
    if (t == 0) bsums[blockIdx.x] = sd[0];
}

__global__ void scan_offsets_kernel(int* __restrict__ bsums, int nb, int* __restrict__ rowptr_tail) {
    __shared__ int sd[128];
    int t = threadIdx.x;
    int v = (t < nb) ? bsums[t] : 0;
    sd[t] = v; __syncthreads();
    for (int off = 1; off < 128; off <<= 1) {
        int x = (t >= off) ? sd[t - off] : 0;
        __syncthreads();
        sd[t] += x;
        __syncthreads();
    }
    if (t < nb) bsums[t] = sd[t] - v;      // exclusive
    if (t == 0) *rowptr_tail = N_EDGES;    // rowptr[n]
}

__global__ void scan_final_kernel(const int* __restrict__ deg, const int* __restrict__ bsums,
                                  int* __restrict__ rowptr, int n) {
    __shared__ int sd[256];
    int t = threadIdx.x;
    int base = blockIdx.x * 1024 + t * 4;
    int v[4], pre[4], s = 0;
    #pragma unroll
    for (int j = 0; j < 4; ++j) {
        int i = base + j;
        v[j] = (i < n) ? deg[i] : 0;
        pre[j] = s; s += v[j];
    }
    sd[t] = s;
    int mine = s;
    __syncthreads();
    for (int off = 1; off < 256; off <<= 1) {
        int x = (t >= off) ? sd[t - off] : 0;
        __syncthreads();
        sd[t] += x;
        __syncthreads();
    }
    int excl = sd[t] - mine + bsums[blockIdx.x];
    #pragma unroll
    for (int j = 0; j < 4; ++j) {
        int i = base + j;
        if (i < n) rowptr[i] = excl + pre[j];
    }
}

// ---------------- counting-sort fill: (src, weight) packed as int2 ----------------
__global__ void fill_kernel(const int* __restrict__ src, const int* __restrict__ dst,
                            const float* __restrict__ dinv, const int* __restrict__ rowptr,
                            int* __restrict__ cursor, int2* __restrict__ csr, int E) {
    int i = blockIdx.x * blockDim.x + threadIdx.x;
    if (i >= E) return;
    int s = src[i], d = dst[i];
    int pos = atomicAdd(&cursor[d], 1);
    float w = dinv[s] * dinv[d];
    csr[rowptr[d] + pos] = make_int2(s, __float_as_int(w));
}

// ---------------- gather (one wave per dst node), 8x-unrolled edge loop ----------------
template<int F, bool BIAS, bool RELU>
__global__ void gather_kernel(const int* __restrict__ rowptr, const int2* __restrict__ csr,
                              const float* __restrict__ dinv,
                              const float* __restrict__ xw, const float* __restrict__ bias,
                              float* __restrict__ out, int n) {
    const int lane = threadIdx.x & 63;
    const int wid0 = (blockIdx.x * blockDim.x + threadIdx.x) >> 6;
    const int nwav = (gridDim.x * blockDim.x) >> 6;
    for (int node = wid0; node < n; node += nwav) {
        float di = dinv[node];
        float selfw = di * di;
        int e0 = rowptr[node], e1 = rowptr[node + 1];
        if (F == 128) {
            const float2 sv = *(const float2*)&xw[(size_t)node * F + lane * 2];
            float ax = sv.x * selfw, ay = sv.y * selfw;
            int e = e0;
            for (; e + 8 <= e1; e += 8) {
                int2 p[8]; float2 v[8];
                #pragma unroll
                for (int u = 0; u < 8; ++u) p[u] = csr[e + u];
                #pragma unroll
                for (int u = 0; u < 8; ++u)
                    v[u] = *(const float2*)&xw[(size_t)p[u].x * F + lane * 2];
                #pragma unroll
                for (int u = 0; u < 8; ++u) {
                    float w = __int_as_float(p[u].y);
                    ax += v[u].x * w; ay += v[u].y * w;
                }
            }
            for (; e + 4 <= e1; e += 4) {
                int2 p[4]; float2 v[4];
                #pragma unroll
                for (int u = 0; u < 4; ++u) p[u] = csr[e + u];
                #pragma unroll
                for (int u = 0; u < 4; ++u)
                    v[u] = *(const float2*)&xw[(size_t)p[u].x * F + lane * 2];
                #pragma unroll
                for (int u = 0; u < 4; ++u) {
                    float w = __int_as_float(p[u].y);
                    ax += v[u].x * w; ay += v[u].y * w;
                }
            }
            for (; e < e1; ++e) {
                int2 p = csr[e];
                float w = __int_as_float(p.y);
                const float2 v = *(const float2*)&xw[(size_t)p.x * F + lane * 2];
                ax += v.x * w; ay += v.y * w;
            }
            if (BIAS) { const float2 bb = *(const float2*)&bias[lane * 2]; ax += bb.x; ay += bb.y; }
            if (RELU) { ax = fmaxf(ax, 0.f); ay = fmaxf(ay, 0.f); }
            *(float2*)&out[(size_t)node * F + lane * 2] = make_float2(ax, ay);
        } else {  // F == 64
            float acc = xw[(size_t)node * F + lane] * selfw;
            int e = e0;
            for (; e + 8 <= e1; e += 8) {
                int2 p[8]; float v[8];
                #pragma unroll
                for (int u = 0; u < 8; ++u) p[u] = csr[e + u];
                #pragma unroll
                for (int u = 0; u < 8; ++u) v[u] = xw[(size_t)p[u].x * F + lane];
                #pragma unroll
                for (int u = 0; u < 8; ++u) acc += v[u] * __int_as_float(p[u].y);
            }
            for (; e < e1; ++e) {
                int2 p = csr[e];
                acc += xw[(size_t)p.x * F + lane] * __int_as_float(p.y);
            }
            if (BIAS) acc += bias[lane];
            if (RELU) acc = fmaxf(acc, 0.f);
            out[(size_t)node * F + lane] = acc;
        }
    }
}

// ---------------- fp32 tiled GEMM, split-chunk TMxTN microtile ----------------
// C[M,N] = A[M,K] @ B[K,N] (+bias, +relu). K%BK==0, N%4==0, TM%4==0, TN%4==0.
// Fragments are float4 chunks at stride BM/RS (rows) / BN/CS (cols) -> lane
// addresses stride 4 floats => <=2-way LDS bank aliasing (free).
template<int BM, int BN, int BK, int TM, int TN, bool ADD_BIAS, bool RELU>
__global__ __launch_bounds__((BM / TM) * (BN / TN)) void gemm_kernel(
        const float* __restrict__ A, const float* __restrict__ B,
        const float* __restrict__ bias, float* __restrict__ Cmat,
        int M, int N, int K) {
    constexpr int NT = (BM / TM) * (BN / TN);
    constexpr int RS = TM / 4;             // row chunks
    constexpr int CS = TN / 4;             // col chunks
    constexpr int AV = BM * BK / 4 / NT;   // float4 loads per thread (A)
    constexpr int BV = BN * BK / 4 / NT;   // float4 loads per thread (B)
    constexpr int KV = BK / 4;             // float4 per A row
    __shared__ float As[BK][BM];
    __shared__ float Bs[BK][BN];

    const int t  = threadIdx.x;
    const int tm = t / (BN / TN);
    const int tn = t % (BN / TN);
    const int m0 = blockIdx.x * BM;
    const int n0 = blockIdx.y * BN;

    float acc[TM][TN] = {};

    for (int k0 = 0; k0 < K; k0 += BK) {
        #pragma unroll
        for (int v = 0; v < AV; ++v) {
            int idx = t + v * NT;          // BM x KV float4 grid
            int row = idx / KV;
            int c4  = (idx % KV) * 4;
            float4 a4 = make_float4(0.f, 0.f, 0.f, 0.f);
            if (m0 + row < M)
                a4 = *(const float4*)&A[(size_t)(m0 + row) * K + k0 + c4];
            As[c4 + 0][row] = a4.x; As[c4 + 1][row] = a4.y;
            As[c4 + 2][row] = a4.z; As[c4 + 3][row] = a4.w;
        }
        #pragma unroll
        for (int v = 0; v < BV; ++v) {
            int idx = t + v * NT;          // BK x (BN/4) float4 grid
            int row = idx / (BN / 4);
            int col = (idx % (BN / 4)) * 4;
            float4 b4 = make_float4(0.f, 0.f, 0.f, 0.f);
            if (n0 + col < N)
                b4 = *(const float4*)&B[(size_t)(k0 + row) * N + n0 + col];
            *(float4*)&Bs[row][col] = b4;
        }
        __syncthreads();
        #pragma unroll
        for (int k = 0; k < BK; ++k) {
            float a[TM], b[TN];
            #pragma unroll
            for (int r = 0; r < RS; ++r)
                *(float4*)&a[r * 4] = *(const float4*)&As[k][(BM / RS) * r + tm * 4];
            #pragma unroll
            for (int c = 0; c < CS; ++c)
                *(float4*)&b[c * 4] = *(const float4*)&Bs[k][(BN / CS) * c + tn * 4];
            #pragma unroll
            for (int i = 0; i < TM; ++i)
                #pragma unroll
                for (int j = 0; j < TN; ++j)
                    acc[i][j] += a[i] * b[j];
        }
        __syncthreads();
    }

    #pragma unroll
    for (int i = 0; i < TM; ++i) {
        int row = m0 + (BM / RS) * (i / 4) + tm * 4 + (i % 4);
        if (row >= M) continue;
        #pragma unroll
        for (int c = 0; c < CS; ++c) {
            int col = n0 + (BN / CS) * c + tn * 4;
            if (col >= N) continue;       // chunks are float4-aligned; N%4==0
            float4 v = make_float4(acc[i][c * 4], acc[i][c * 4 + 1],
                                   acc[i][c * 4 + 2], acc[i][c * 4 + 3]);
            if (ADD_BIAS) {
                v.x += bias[col]; v.y += bias[col + 1];
                v.z += bias[col + 2]; v.w += bias[col + 3];
            }
            if (RELU) {
                v.x = fmaxf(v.x, 0.f); v.y = fmaxf(v.y, 0.f);
                v.z = fmaxf(v.z, 0.f); v.w = fmaxf(v.w, 0.f);
            }
            *(float4*)&Cmat[(size_t)row * N + col] = v;
        }
    }
}

extern "C" void kernel_launch(void* const* d_in, const int* in_sizes, int n_in,
                              void* d_out, int out_size, void* d_ws, size_t ws_size,
                              hipStream_t stream) {
    const float* x   = (const float*)d_in[0];
    const int*   ei  = (const int*)d_in[1];
    const float* W1  = (const float*)d_in[2];
    const float* b1  = (const float*)d_in[3];
    const float* W2  = (const float*)d_in[4];
    const float* b2  = (const float*)d_in[5];
    const float* Wfc = (const float*)d_in[6];
    const float* bfc = (const float*)d_in[7];
    float* out = (float*)d_out;

    const int n = N_NODES, E = N_EDGES;
    const int* src = ei;
    const int* dst = ei + E;

    char* ws = (char*)d_ws;
    int*   deg     = (int*)(ws + 0);             // 400 KB (reused as cursor)
    float* dinv    = (float*)(ws + 409600);      // 400 KB
    int*   rowptr  = (int*)(ws + 819200);        // ~400 KB
    int*   bsums   = (int*)(ws + 1228800);       // 512 B
    int2*  csr     = (int2*)(ws + 1229312);      // 12.8 MB (packed src+w)
    float* bufA    = (float*)(ws + 14029312);    // 51.2 MB  (aggx, then h1w2)
    float* bufB    = (float*)(ws + 65229312);    // 102.4 MB (h1, then h2)

    const int nb = (n + 1023) / 1024;  // 98 scan blocks

    // ---- CSR build (by dst) ----
    hipMemsetAsync(deg, 0, (size_t)n * sizeof(int), stream);
    deg_kernel<<<(E + 255) / 256, 256, 0, stream>>>(dst, deg, E);
    dinv_kernel<<<(n + 255) / 256, 256, 0, stream>>>(deg, dinv, n);
    scan_sums_kernel<<<nb, 256, 0, stream>>>(deg, bsums, n);
    scan_offsets_kernel<<<1, 128, 0, stream>>>(bsums, nb, rowptr + n);
    scan_final_kernel<<<nb, 256, 0, stream>>>(deg, bsums, rowptr, n);
    hipMemsetAsync(deg, 0, (size_t)n * sizeof(int), stream);  // deg -> cursor
    fill_kernel<<<(E + 255) / 256, 256, 0, stream>>>(src, dst, dinv, rowptr, deg, csr, E);

    // ---- layer 1: aggx = A_hat @ x  [100k,128]  (gather FIRST — smaller footprint) ----
    gather_kernel<128, false, false><<<2048, 256, 0, stream>>>(
        rowptr, csr, dinv, x, nullptr, bufA, n);
    // h1 = relu(aggx @ W1 + b1)  [100k,256]
    gemm_kernel<128, 128, 32, 8, 16, true, true><<<dim3((n + 127) / 128, 2), 128, 0, stream>>>(
        bufA, W1, b1, bufB, n, 256, 128);

    // ---- layer 2: h1w2 = h1 @ W2  [100k,64]; gather + bias ----
    gemm_kernel<256, 64, 32, 16, 8, false, false><<<dim3((n + 255) / 256, 1), 128, 0, stream>>>(
        bufB, W2, nullptr, bufA, n, 64, 256);
    gather_kernel<64, true, false><<<2048, 256, 0, stream>>>(
        rowptr, csr, dinv, bufA, b2, bufB, n);

    // ---- FC: out = h2 @ Wfc + bfc  [100k,40] ----
    gemm_kernel<256, 64, 32, 16, 8, true, false><<<dim3((n + 255) / 256, 1), 128, 0, stream>>>(
        bufB, Wfc, bfc, out, n, 40, 64);
}

// Round 9
// 585.937 us; speedup vs baseline: 1.2018x; 1.2018x over previous
//
#include <hip/hip_runtime.h>

#define N_NODES 100000
#define N_EDGES 1600000

// ---------------- degree ----------------
__global__ void deg_kernel(const int* __restrict__ dst, int* __restrict__ deg, int E) {
    int i = blockIdx.x * blockDim.x + threadIdx.x;
    if (i < E) atomicAdd(&deg[dst[i]], 1);
}

__global__ void dinv_kernel(const int* __restrict__ deg, float* __restrict__ dinv, int n) {
    int i = blockIdx.x * blockDim.x + threadIdx.x;
    if (i < n) dinv[i] = rsqrtf((float)(deg[i] + 1));   // +1 = self-loop
}

// ---------------- exclusive scan of deg -> rowptr (3 passes) ----------------
__global__ void scan_sums_kernel(const int* __restrict__ deg, int* __restrict__ bsums, int n) {
    __shared__ int sd[256];
    int t = threadIdx.x;
    int base = blockIdx.x * 1024 + t * 4;
    int s = 0;
    #pragma unroll
    for (int j = 0; j < 4; ++j) { int i = base + j; if (i < n) s += deg[i]; }
    sd[t] = s; __syncthreads();
    for (int off = 128; off > 0; off >>= 1) {
        if (t < off) sd[t] += sd[t + off];
        __syncthreads();
    }
    if (t == 0) bsums[blockIdx.x] = sd[0];
}

__global__ void scan_offsets_kernel(int* __restrict__ bsums, int nb, int* __restrict__ rowptr_tail) {
    __shared__ int sd[128];
    int t = threadIdx.x;
    int v = (t < nb) ? bsums[t] : 0;
    sd[t] = v; __syncthreads();
    for (int off = 1; off < 128; off <<= 1) {
        int x = (t >= off) ? sd[t - off] : 0;
        __syncthreads();
        sd[t] += x;
        __syncthreads();
    }
    if (t < nb) bsums[t] = sd[t] - v;      // exclusive
    if (t == 0) *rowptr_tail = N_EDGES;    // rowptr[n]
}

__global__ void scan_final_kernel(const int* __restrict__ deg, const int* __restrict__ bsums,
                                  int* __restrict__ rowptr, int n) {
    __shared__ int sd[256];
    int t = threadIdx.x;
    int base = blockIdx.x * 1024 + t * 4;
    int v[4], pre[4], s = 0;
    #pragma unroll
    for (int j = 0; j < 4; ++j) {
        int i = base + j;
        v[j] = (i < n) ? deg[i] : 0;
        pre[j] = s; s += v[j];
    }
    sd[t] = s;
    int mine = s;
    __syncthreads();
    for (int off = 1; off < 256; off <<= 1) {
        int x = (t >= off) ? sd[t - off] : 0;
        __syncthreads();
        sd[t] += x;
        __syncthreads();
    }
    int excl = sd[t] - mine + bsums[blockIdx.x];
    #pragma unroll
    for (int j = 0; j < 4; ++j) {
        int i = base + j;
        if (i < n) rowptr[i] = excl + pre[j];
    }
}

// ---------------- counting-sort fill: (src, weight) packed as int2 ----------------
__global__ void fill_kernel(const int* __restrict__ src, const int* __restrict__ dst,
                            const float* __restrict__ dinv, const int* __restrict__ rowptr,
                            int* __restrict__ cursor, int2* __restrict__ csr, int E) {
    int i = blockIdx.x * blockDim.x + threadIdx.x;
    if (i >= E) return;
    int s = src[i], d = dst[i];
    int pos = atomicAdd(&cursor[d], 1);
    float w = dinv[s] * dinv[d];
    csr[rowptr[d] + pos] = make_int2(s, __float_as_int(w));
}

// ---------------- W2fc = W2 @ Wfc  [256,40]; bfc2 = b2 @ Wfc + bfc ----------------
__global__ __launch_bounds__(256) void w2fc_kernel(
        const float* __restrict__ W2, const float* __restrict__ Wfc,
        const float* __restrict__ b2, const float* __restrict__ bfc,
        float* __restrict__ W2fc, float* __restrict__ bfc2) {
    __shared__ float wf[64 * 40];
    int t = threadIdx.x;
    for (int i = t; i < 64 * 40; i += 256) wf[i] = Wfc[i];
    __syncthreads();
    float acc[40];
    #pragma unroll
    for (int c = 0; c < 40; ++c) acc[c] = 0.f;
    for (int k = 0; k < 64; ++k) {
        float a = W2[t * 64 + k];
        #pragma unroll
        for (int c = 0; c < 40; ++c) acc[c] += a * wf[k * 40 + c];
    }
    #pragma unroll
    for (int c = 0; c < 40; ++c) W2fc[t * 40 + c] = acc[c];
    if (t < 40) {
        float s = bfc[t];
        for (int k = 0; k < 64; ++k) s += b2[k] * wf[k * 40 + t];
        bfc2[t] = s;
    }
}

// ---------------- gather (one wave per dst node), 8x-unrolled edge loop ----------------
// F=128: lane owns float2. F=40: lanes 0..39 own 1 float. Self-loop in init.
template<int F, bool BIAS, bool RELU>
__global__ void gather_kernel(const int* __restrict__ rowptr, const int2* __restrict__ csr,
                              const float* __restrict__ dinv,
                              const float* __restrict__ xw, const float* __restrict__ bias,
                              float* __restrict__ out, int n) {
    const int lane = threadIdx.x & 63;
    const int wid0 = (blockIdx.x * blockDim.x + threadIdx.x) >> 6;
    const int nwav = (gridDim.x * blockDim.x) >> 6;
    for (int node = wid0; node < n; node += nwav) {
        float di = dinv[node];
        float selfw = di * di;
        int e0 = rowptr[node], e1 = rowptr[node + 1];
        if (F == 128) {
            const float2 sv = *(const float2*)&xw[(size_t)node * F + lane * 2];
            float ax = sv.x * selfw, ay = sv.y * selfw;
            int e = e0;
            for (; e + 8 <= e1; e += 8) {
                int2 p[8]; float2 v[8];
                #pragma unroll
                for (int u = 0; u < 8; ++u) p[u] = csr[e + u];
                #pragma unroll
                for (int u = 0; u < 8; ++u)
                    v[u] = *(const float2*)&xw[(size_t)p[u].x * F + lane * 2];
                #pragma unroll
                for (int u = 0; u < 8; ++u) {
                    float w = __int_as_float(p[u].y);
                    ax += v[u].x * w; ay += v[u].y * w;
                }
            }
            for (; e + 4 <= e1; e += 4) {
                int2 p[4]; float2 v[4];
                #pragma unroll
                for (int u = 0; u < 4; ++u) p[u] = csr[e + u];
                #pragma unroll
                for (int u = 0; u < 4; ++u)
                    v[u] = *(const float2*)&xw[(size_t)p[u].x * F + lane * 2];
                #pragma unroll
                for (int u = 0; u < 4; ++u) {
                    float w = __int_as_float(p[u].y);
                    ax += v[u].x * w; ay += v[u].y * w;
                }
            }
            for (; e < e1; ++e) {
                int2 p = csr[e];
                float w = __int_as_float(p.y);
                const float2 v = *(const float2*)&xw[(size_t)p.x * F + lane * 2];
                ax += v.x * w; ay += v.y * w;
            }
            if (BIAS) { const float2 bb = *(const float2*)&bias[lane * 2]; ax += bb.x; ay += bb.y; }
            if (RELU) { ax = fmaxf(ax, 0.f); ay = fmaxf(ay, 0.f); }
            *(float2*)&out[(size_t)node * F + lane * 2] = make_float2(ax, ay);
        } else {  // F == 40: lanes 0..39 active (clamped loads, guarded store)
            const int cl = lane < F ? lane : F - 1;
            float acc = xw[(size_t)node * F + cl] * selfw;
            int e = e0;
            for (; e + 8 <= e1; e += 8) {
                int2 p[8]; float v[8];
                #pragma unroll
                for (int u = 0; u < 8; ++u) p[u] = csr[e + u];
                #pragma unroll
                for (int u = 0; u < 8; ++u) v[u] = xw[(size_t)p[u].x * F + cl];
                #pragma unroll
                for (int u = 0; u < 8; ++u) acc += v[u] * __int_as_float(p[u].y);
            }
            for (; e < e1; ++e) {
                int2 p = csr[e];
                acc += xw[(size_t)p.x * F + cl] * __int_as_float(p.y);
            }
            if (BIAS) acc += bias[cl];
            if (RELU) acc = fmaxf(acc, 0.f);
            if (lane < F) out[(size_t)node * F + lane] = acc;
        }
    }
}

// ---------------- fp32 tiled GEMM, split-chunk 8x8 microtile, swizzled A-staging ----
// C[M,N] = A[M,K] @ B[K,N] (+bias, +relu). K%BK==0, N%4==0, BK=32.
// As stored [BK][BM] with column index XOR p(k), p(k)=8*((k>>2)&3):
//   staging writes land 2 lanes/bank (free), fragment reads stay conflict-free.
template<int BM, int BN, bool ADD_BIAS, bool RELU>
__global__ __launch_bounds__((BM / 8) * (BN / 8)) void gemm_kernel(
        const float* __restrict__ A, const float* __restrict__ B,
        const float* __restrict__ bias, float* __restrict__ Cmat,
        int M, int N, int K) {
    constexpr int TM = 8, TN = 8, BK = 32;
    constexpr int NT = (BM / TM) * (BN / TN);
    constexpr int AV = BM * BK / 4 / NT;   // float4 loads per thread (A)
    constexpr int BV = BN * BK / 4 / NT;   // float4 loads per thread (B)
    constexpr int KV = BK / 4;             // float4 per A row
    __shared__ float As[BK][BM];
    __shared__ float Bs[BK][BN];

    const int t  = threadIdx.x;
    const int tm = t / (BN / TN);
    const int tn = t % (BN / TN);
    const int m0 = blockIdx.x * BM;
    const int n0 = blockIdx.y * BN;

    float acc[TM][TN] = {};

    for (int k0 = 0; k0 < K; k0 += BK) {
        #pragma unroll
        for (int v = 0; v < AV; ++v) {
            int idx = t + v * NT;          // BM x KV float4 grid
            int row = idx / KV;
            int c4  = (idx % KV) * 4;
            int pk  = 8 * ((c4 >> 2) & 3); // same for c4..c4+3
            float4 a4 = make_float4(0.f, 0.f, 0.f, 0.f);
            if (m0 + row < M)
                a4 = *(const float4*)&A[(size_t)(m0 + row) * K + k0 + c4];
            As[c4 + 0][row ^ pk] = a4.x; As[c4 + 1][row ^ pk] = a4.y;
            As[c4 + 2][row ^ pk] = a4.z; As[c4 + 3][row ^ pk] = a4.w;
        }
        #pragma unroll
        for (int v = 0; v < BV; ++v) {
            int idx = t + v * NT;          // BK x (BN/4) float4 grid
            int row = idx / (BN / 4);
            int col = (idx % (BN / 4)) * 4;
            float4 b4 = make_float4(0.f, 0.f, 0.f, 0.f);
            if (n0 + col < N)
                b4 = *(const float4*)&B[(size_t)(k0 + row) * N + n0 + col];
            *(float4*)&Bs[row][col] = b4;
        }
        __syncthreads();
        #pragma unroll
        for (int k = 0; k < BK; ++k) {
            const int pk = 8 * ((k >> 2) & 3);
            float a[TM], b[TN];
            #pragma unroll
            for (int r = 0; r < 2; ++r)
                *(float4*)&a[r * 4] = *(const float4*)&As[k][(tm * 4 + (BM / 2) * r) ^ pk];
            #pragma unroll
            for (int c = 0; c < 2; ++c)
                *(float4*)&b[c * 4] = *(const float4*)&Bs[k][tn * 4 + (BN / 2) * c];
            #pragma unroll
            for (int i = 0; i < TM; ++i)
                #pragma unroll
                for (int j = 0; j < TN; ++j)
                    acc[i][j] += a[i] * b[j];
        }
        __syncthreads();
    }

    #pragma unroll
    for (int i = 0; i < TM; ++i) {
        int row = m0 + (BM / 2) * (i / 4) + tm * 4 + (i % 4);
        if (row >= M) continue;
        #pragma unroll
        for (int c = 0; c < 2; ++c) {
            int col = n0 + (BN / 2) * c + tn * 4;
            if (col >= N) continue;       // chunks float4-aligned; N%4==0
            float4 v = make_float4(acc[i][c * 4], acc[i][c * 4 + 1],
                                   acc[i][c * 4 + 2], acc[i][c * 4 + 3]);
            if (ADD_BIAS) {
                v.x += bias[col]; v.y += bias[col + 1];
                v.z += bias[col + 2]; v.w += bias[col + 3];
            }
            if (RELU) {
                v.x = fmaxf(v.x, 0.f); v.y = fmaxf(v.y, 0.f);
                v.z = fmaxf(v.z, 0.f); v.w = fmaxf(v.w, 0.f);
            }
            *(float4*)&Cmat[(size_t)row * N + col] = v;
        }
    }
}

extern "C" void kernel_launch(void* const* d_in, const int* in_sizes, int n_in,
                              void* d_out, int out_size, void* d_ws, size_t ws_size,
                              hipStream_t stream) {
    const float* x   = (const float*)d_in[0];
    const int*   ei  = (const int*)d_in[1];
    const float* W1  = (const float*)d_in[2];
    const float* b1  = (const float*)d_in[3];
    const float* W2  = (const float*)d_in[4];
    const float* b2  = (const float*)d_in[5];
    const float* Wfc = (const float*)d_in[6];
    const float* bfc = (const float*)d_in[7];
    float* out = (float*)d_out;

    const int n = N_NODES, E = N_EDGES;
    const int* src = ei;
    const int* dst = ei + E;

    char* ws = (char*)d_ws;
    int*   deg     = (int*)(ws + 0);             // 400 KB (reused as cursor)
    float* dinv    = (float*)(ws + 409600);      // 400 KB
    int*   rowptr  = (int*)(ws + 819200);        // ~400 KB
    int*   bsums   = (int*)(ws + 1219584);       // 512 B
    float* W2fc    = (float*)(ws + 1220096);     // 40 KB  [256,40]
    float* bfc2    = (float*)(ws + 1261056);     // 160 B
    int2*  csr     = (int2*)(ws + 1261568);      // 12.8 MB (packed src+w)
    float* bufA    = (float*)(ws + 14061568);    // 51.2 MB  (aggx, then h1w2fc)
    float* bufB    = (float*)(ws + 65261568);    // 102.4 MB (h1)

    const int nb = (n + 1023) / 1024;  // 98 scan blocks

    // ---- CSR build (by dst) + fused-FC weight precompute ----
    hipMemsetAsync(deg, 0, (size_t)n * sizeof(int), stream);
    deg_kernel<<<(E + 255) / 256, 256, 0, stream>>>(dst, deg, E);
    dinv_kernel<<<(n + 255) / 256, 256, 0, stream>>>(deg, dinv, n);
    scan_sums_kernel<<<nb, 256, 0, stream>>>(deg, bsums, n);
    scan_offsets_kernel<<<1, 128, 0, stream>>>(bsums, nb, rowptr + n);
    scan_final_kernel<<<nb, 256, 0, stream>>>(deg, bsums, rowptr, n);
    hipMemsetAsync(deg, 0, (size_t)n * sizeof(int), stream);  // deg -> cursor
    fill_kernel<<<(E + 255) / 256, 256, 0, stream>>>(src, dst, dinv, rowptr, deg, csr, E);
    w2fc_kernel<<<1, 256, 0, stream>>>(W2, Wfc, b2, bfc, W2fc, bfc2);

    // ---- layer 1: aggx = A_hat @ x  [100k,128]; h1 = relu(aggx @ W1 + b1) ----
    gather_kernel<128, false, false><<<2048, 256, 0, stream>>>(
        rowptr, csr, dinv, x, nullptr, bufA, n);
    gemm_kernel<128, 128, true, true><<<dim3((n + 127) / 128, 2), 256, 0, stream>>>(
        bufA, W1, b1, bufB, n, 256, 128);

    // ---- layer 2 + FC folded: out = A_hat @ (h1 @ W2fc) + bfc2 ----
    gemm_kernel<256, 64, false, false><<<dim3((n + 255) / 256, 1), 256, 0, stream>>>(
        bufB, W2fc, nullptr, bufA, n, 40, 256);
    gather_kernel<40, true, false><<<2048, 256, 0, stream>>>(
        rowptr, csr, dinv, bufA, bfc2, out, n);
}